// Round 18
// baseline (119.433 us; speedup 1.0000x reference)
//
#include <hip/hip_runtime.h>
#include <hip/hip_bf16.h>
#include <hip/hip_fp8.h>

#define PI_D 3.14159265358979323846
#define L_TOTAL 2097152
#define NFRAMES 4105      // 1 + L/511
#define NBLK    4108
#define MROWS_P 8216
#define KP      512       // 511 padded
#define NDIM    2048      // 1024 bins * (Re,Im)

// fp8 (OCP e4m3) permuted global layout for Ap and Bp, in 8B units of 8 fp8:
//   unit8(row, kc) = (row>>4)*1024 + kc*16 + (row&15),  kc = k/8 in [0,64)
// BK=64 staging: LDS = two 8KB K-step chunks, each in the verified r16 layout
// (dst = chunkBase + tid*16 — wave-uniform base + lane*16, per the
// global_load_lds constraint; r17's g*1024+u*16 mapping violated it -> NaN).

// Fused GEMM+combine: M-tiles step 56 hop-blocks (112 rows, 16-aligned) so each
// frame's 4 hop-blocks live in one tile; C-tile goes to LDS (bf16), combine
// reads it there. Pt global buffer eliminated (r16, verified absmax 4.0).
#define MTILES 74             // ceil(4105/56)
#define NTILES 16
#define INVW_BLOCKS 256       // 512-thread invw blocks
#define GC_BLOCKS (MTILES * NTILES)

// prep branch order: LONGEST-latency bodies first
#define BURG_BLOCKS   512
#define FRAMES_BLOCKS 1040   // 4160 waves, one per hop-block
#define BASIS_BLOCKS  256    // 1024 waves, one per frequency f
#define SARR_BLOCKS   17     // 4352 S entries (also zeroes accumulators)
#define PREP_BLOCKS   (BURG_BLOCKS + FRAMES_BLOCKS + BASIS_BLOCKS + SARR_BLOCKS)

typedef __attribute__((ext_vector_type(8))) short short8;
typedef __attribute__((ext_vector_type(4))) float floatx4;
typedef float floatx4u __attribute__((ext_vector_type(4), aligned(4)));

typedef __attribute__((address_space(1))) void gvoid_as1;
typedef __attribute__((address_space(3))) void lvoid_as3;

__device__ __forceinline__ void gld_lds16(const void* g, void* l) {
    __builtin_amdgcn_global_load_lds((gvoid_as1*)g, (lvoid_as3*)l, 16, 0, 0);
}

__device__ __forceinline__ unsigned int pk4_e4m3(float a, float b, float c, float d) {
    __hip_fp8_e4m3 q0(a), q1(b), q2(c), q3(d);
    return (unsigned int)q0.__x | ((unsigned int)q1.__x << 8)
         | ((unsigned int)q2.__x << 16) | ((unsigned int)q3.__x << 24);
}

__device__ __forceinline__ float xorall(float v) {
    v += __shfl_xor(v, 1, 64);
    v += __shfl_xor(v, 2, 64);
    v += __shfl_xor(v, 4, 64);
    v += __shfl_xor(v, 8, 64);
    v += __shfl_xor(v, 16, 64);
    v += __shfl_xor(v, 32, 64);
    return v;
}

__device__ __forceinline__ float wave_reduce(float v) {
    v += __shfl_down(v, 32, 64);
    v += __shfl_down(v, 16, 64);
    v += __shfl_down(v, 8, 64);
    v += __shfl_down(v, 4, 64);
    v += __shfl_down(v, 2, 64);
    v += __shfl_down(v, 1, 64);
    return v;
}

// ---------------- frames branch: build Ap (fp8 e4m3, permuted layout) --------------
__device__ __forceinline__ void frames_body(int bid, int tid,
                                            const float* __restrict__ x,
                                            const float* __restrict__ y,
                                            char* __restrict__ A) {
    const int lane = tid & 63;
    const int b = bid * 4 + (tid >> 6);          // 0..4159
    const int p0 = b * 511 + lane * 8 - 1023;
    float xv[8], yv[8];
    if (p0 >= 0 && p0 + 8 <= L_TOTAL) {
        floatx4u x0 = *(const floatx4u*)(x + p0);
        floatx4u x1 = *(const floatx4u*)(x + p0 + 4);
        floatx4u y0 = *(const floatx4u*)(y + p0);
        floatx4u y1 = *(const floatx4u*)(y + p0 + 4);
#pragma unroll
        for (int e = 0; e < 4; e++) { xv[e] = x0[e]; xv[4 + e] = x1[e]; }
#pragma unroll
        for (int e = 0; e < 4; e++) { yv[e] = y0[e]; yv[4 + e] = y1[e]; }
    } else {
#pragma unroll
        for (int e = 0; e < 8; e++) {
            int p = p0 + e;
            if (p < 0) p = -p;
            else if (p >= L_TOTAL) p = 2 * L_TOTAL - 2 - p;
            xv[e] = x[p];
            yv[e] = y[p];
        }
    }
    int4 pk;
    pk.x = (int)pk4_e4m3(xv[0], xv[1], xv[2], xv[3]);
    pk.y = (int)pk4_e4m3(xv[4], xv[5], xv[6], xv[7]);
    pk.z = (int)pk4_e4m3(yv[0], yv[1], yv[2], yv[3]);
    pk.w = (int)pk4_e4m3(yv[4], yv[5], yv[6], yv[7]);
    *(int4*)(A + (size_t)(b >> 3) * 8192 + lane * 128 + (b & 7) * 16) = pk;
}

// ---------------- basis branch: Bp (fp8 e4m3, permuted layout) ---------------------
__device__ __forceinline__ void basis_body(int bid, int tid,
                                           char* __restrict__ Bt) {
    const int lane = tid & 63;
    const int f = bid * 4 + (tid >> 6);          // 0..1023
    const int n0 = lane * 8;
    const int m0 = (f * n0) % 2046;
    float s, c, ss, cs;
    __sincosf((float)m0 * (float)(PI_D / 1023.0), &s, &c);
    __sincosf((float)f * (float)(PI_D / 1023.0), &ss, &cs);
    float cv[8], sv[8];
#pragma unroll
    for (int e = 0; e < 8; e++) {
        const int n = n0 + e;
        const bool valid = n < 511;
        cv[e] = valid ? c : 0.f;
        sv[e] = valid ? -s : 0.f;
        float c2 = c * cs - s * ss;
        float s2 = s * cs + c * ss;
        c = c2; s = s2;
    }
    int4 pk;
    pk.x = (int)pk4_e4m3(cv[0], cv[1], cv[2], cv[3]);
    pk.y = (int)pk4_e4m3(cv[4], cv[5], cv[6], cv[7]);
    pk.z = (int)pk4_e4m3(sv[0], sv[1], sv[2], sv[3]);
    pk.w = (int)pk4_e4m3(sv[4], sv[5], sv[6], sv[7]);
    *(int4*)(Bt + (size_t)(f >> 3) * 8192 + lane * 128 + (f & 7) * 16) = pk;
}

// ---------------- S branch: tail-sample table + accumulator zeroing ----------------
__device__ __forceinline__ void sarr_body(int bid, int tid,
                                          const float* __restrict__ x,
                                          const float* __restrict__ y,
                                          float4* __restrict__ S,
                                          float* __restrict__ wsf) {
    if (bid < 8) wsf[bid * 256 + tid] = 0.f;   // zero mse_sum + invW
    const int b = bid * 256 + tid;          // 0..4351
    int p0 = 511 * b - 1023;
    int p1 = p0 + 1;
    int m0 = (p0 < 0) ? -p0 : ((p0 >= L_TOTAL) ? 2 * L_TOTAL - 2 - p0 : p0);
    int m1 = (p1 < 0) ? -p1 : ((p1 >= L_TOTAL) ? 2 * L_TOTAL - 2 - p1 : p1);
    S[b] = make_float4(x[m0], x[m1], y[m0], y[m1]);
}

// ---------------- burg branch: one WAVE per 1024-sample audio block ----------------
__device__ __forceinline__ void burg_body(int bid, int tid,
                                          const float* __restrict__ y,
                                          float* __restrict__ ar_out) {
    const int lane = tid & 63;
    const int wid = tid >> 6;
    const int blk = bid * 4 + wid;
    const float4* yb4 = (const float4*)(y + (size_t)blk * 1024) + lane * 4;

    float t[16];
#pragma unroll
    for (int q = 0; q < 4; q++) {
        float4 v = yb4[q];
        t[q * 4 + 0] = v.x; t[q * 4 + 1] = v.y;
        t[q * 4 + 2] = v.z; t[q * 4 + 3] = v.w;
    }
    float b[16], f[16];
#pragma unroll
    for (int r = 0; r < 16; r++) b[r] = t[r];
#pragma unroll
    for (int r = 0; r < 15; r++) f[r] = t[r + 1];
    {
        float nb = __shfl_down(t[0], 1, 64);
        f[15] = (lane == 63) ? 0.f : nb;
        if (lane == 63) b[15] = 0.f;
    }

    float den = 0.f;
#pragma unroll
    for (int r = 0; r < 16; r++) den += f[r] * f[r] + b[r] * b[r];
    den = xorall(den);

    float ar_s[13];
    ar_s[0] = 1.f;
#pragma unroll
    for (int j = 1; j < 13; j++) ar_s[j] = 0.f;

#pragma unroll
    for (int i = 0; i < 12; i++) {
        float num = 0.f;
#pragma unroll
        for (int r = 0; r < 16; r++) num += f[r] * b[r];
        num = xorall(num);
        const float k = -2.f * num / den;

        float fu[16], bu[16];
#pragma unroll
        for (int r = 0; r < 16; r++) {
            fu[r] = f[r] + k * b[r];
            bu[r] = b[r] + k * f[r];
        }
        const float f0 = __shfl(fu[0], 0, 64);
        const int pos = 1022 - i;
        const int L = pos >> 4, S = pos & 15;
        const float blast = __shfl(bu[S], L, 64);

        den = (1.f - k * k) * den - blast * blast - f0 * f0;

        float nf = __shfl_down(fu[0], 1, 64);
#pragma unroll
        for (int r = 0; r < 15; r++) f[r] = fu[r + 1];
        f[15] = (lane == 63) ? 0.f : nf;
#pragma unroll
        for (int r = 0; r < 16; r++) b[r] = bu[r];
        if (lane == L) b[S] = 0.f;

        float tmp[13];
#pragma unroll
        for (int js = 1; js <= i + 1; js++) tmp[js] = ar_s[js] + k * ar_s[i + 1 - js];
#pragma unroll
        for (int js = 1; js <= i + 1; js++) ar_s[js] = tmp[js];
    }

#pragma unroll
    for (int j = 0; j < 12; j++)
        if (lane == j) ar_out[(size_t)blk * 12 + j] = ar_s[j];
}

// ---------------- fused prep ----------------
__global__ __launch_bounds__(256) void prep_kernel(const float* __restrict__ x,
                                                   const float* __restrict__ y,
                                                   char* __restrict__ A,
                                                   char* __restrict__ Bt,
                                                   float4* __restrict__ S,
                                                   float* __restrict__ ar,
                                                   float* __restrict__ wsf) {
    const int bid = blockIdx.x;
    const int tid = threadIdx.x;
    if (bid < BURG_BLOCKS) {
        burg_body(bid, tid, y, ar);
    } else if (bid < BURG_BLOCKS + FRAMES_BLOCKS) {
        frames_body(bid - BURG_BLOCKS, tid, x, y, A);
    } else if (bid < BURG_BLOCKS + FRAMES_BLOCKS + BASIS_BLOCKS) {
        basis_body(bid - BURG_BLOCKS - FRAMES_BLOCKS, tid, Bt);
    } else {
        sarr_body(bid - BURG_BLOCKS - FRAMES_BLOCKS - BASIS_BLOCKS, tid, x, y, S, wsf);
    }
}

// ---------------- invw body (512-thread): invW[f] += sum over 16 b's ---------------
__device__ __forceinline__ void invw_body(int bid, int tid, char* smem,
                                          const float* __restrict__ ar,
                                          float* __restrict__ invW) {
    float (*sar)[12] = (float(*)[12])smem;
    const int f = (bid & 1) * 512 + tid;     // 0..1023
    const int b0 = (bid >> 1) * 16;
    if (tid < 16 * 12) ((float*)sar)[tid] = ar[(size_t)b0 * 12 + tid];
    __syncthreads();

    const float omega = (float)(PI_D / 1024.0) * (float)f;
    float sw, cw;
    __sincosf(omega, &sw, &cw);

    float acc = 0.f;
#pragma unroll 4
    for (int bb = 0; bb < 16; bb++) {
        float a0 = sar[bb][0];
        float nr = a0, ni = 0.f, dr = a0, di = 0.f;
        float er = 1.f, ei = 0.f;
        float g1p = 1.f, g2p = 1.f;
#pragma unroll
        for (int j = 1; j < 12; j++) {
            float er2 = er * cw + ei * sw;
            float ei2 = ei * cw - er * sw;
            er = er2; ei = ei2;
            g1p *= 0.92f; g2p *= 0.6f;
            float aj = sar[bb][j];
            float a1 = aj * g1p, a2 = aj * g2p;
            nr += a2 * er; ni += a2 * ei;
            dr += a1 * er; di += a1 * ei;
            float D = dr * dr + di * di;
            float Nn = nr * nr + ni * ni;
            acc += D * __builtin_amdgcn_rsqf(D * Nn);
        }
    }
    atomicAdd(&invW[f], acc);
}

// ---------------- fused GEMM + combine body (no Pt), BK=64 -------------------------
// LDS: chunk ks at [ks*8192, +8192), each chunk in r16 layout (A 4K | B 4K),
// staged via dst = chunkBase + tid*16 (wave-uniform + lane*16 -- HW constraint).
__device__ __forceinline__ void gemm_combine_body(
    int bx, int by, int tid, char* smem,
    const char* __restrict__ A, const char* __restrict__ Bt,
    const float4* __restrict__ S, float* __restrict__ mse_sum) {
    char* stg = smem;                                    // 16 KB staging
    unsigned short* Cl = (unsigned short*)(smem + 16384); // 128x128 bf16 = 32 KB
    float* msePart = (float*)(smem + 16384 + 32768);      // 64 floats

    const int lane = tid & 63;
    const int w = tid >> 6;
    const int wm = w >> 1, wn = w & 1;
    const int q = lane >> 4, l15 = lane & 15;
    const int tileN = bx * 128;
    const int tileMblk = by * 56;            // hop-block base
    const int tileM = tileMblk * 2;          // row base (112*by, 16-aligned)

    if (tid < 64) msePart[tid] = 0.f;

    floatx4 acc[2][4];
#pragma unroll
    for (int i = 0; i < 2; i++)
#pragma unroll
        for (int j = 0; j < 4; j++) acc[i][j] = (floatx4){0.f, 0.f, 0.f, 0.f};

    // global: per row-block g the iter's 1KB run is [g*8192 + it*1024, +1024);
    // thread handles unit u of the first 512B (ks=0) and the same u of ks=1.
    const int t8 = tid & 255;
    const int g = t8 >> 5;              // row/col-block 0..7
    const int u = t8 & 31;              // 16B unit within 512B K-step run
    const char* p = ((tid < 256)
        ? A + (((size_t)(tileM >> 4) + g) << 13)
        : Bt + (((size_t)(tileN >> 4) + g) << 13)) + u * 16;

    for (int it = 0; it < KP / 64; it++) {
        gld_lds16(p, stg + tid * 16);              // ks=0 chunk
        gld_lds16(p + 512, stg + 8192 + tid * 16); // ks=1 chunk
        p += 1024;
        __syncthreads();

#pragma unroll
        for (int ks = 0; ks < 2; ks++) {
            long af[2], bf[4];
#pragma unroll
            for (int sm = 0; sm < 2; sm++)
                af[sm] = *(const long*)(stg + ks * 8192 + (wm * 2 + sm) * 512 + lane * 8);
#pragma unroll
            for (int sn = 0; sn < 4; sn++)
                bf[sn] = *(const long*)(stg + ks * 8192 + 4096 + (wn * 4 + sn) * 512 + lane * 8);
#pragma unroll
            for (int sm = 0; sm < 2; sm++)
#pragma unroll
                for (int sn = 0; sn < 4; sn++)
                    acc[sm][sn] = __builtin_amdgcn_mfma_f32_16x16x32_fp8_fp8(
                        af[sm], bf[sn], acc[sm][sn], 0, 0, 0);
        }
        __syncthreads();
    }

    // C -> LDS bf16 [row][col]; C/D layout: col=lane&15 (N), row=quad*4+reg (M)
#pragma unroll
    for (int sm = 0; sm < 2; sm++) {
        const int rowB = wm * 32 + sm * 16 + q * 4;
#pragma unroll
        for (int sn = 0; sn < 4; sn++) {
            const int col = wn * 64 + sn * 16 + l15;
#pragma unroll
            for (int r = 0; r < 4; r++) {
                __hip_bfloat16 h = __float2bfloat16(acc[sm][sn][r]);
                Cl[(rowB + r) * 128 + col] = *(unsigned short*)&h;
            }
        }
    }
    __syncthreads();

    // combine: lane -> f_local; wave -> 7-frame group; rolling 4-block window
    const int fg = (tileN >> 1) + lane;      // global f 0..1023
    float wc[4], ws[4];
    wc[0] = 1.f; ws[0] = 0.f;
#pragma unroll
    for (int h = 1; h < 4; h++) {
        int m = (511 * h * fg) % 2046;
        float s, c;
        __sincosf((float)m * (float)(PI_D / 1023.0), &s, &c);
        wc[h] = c; ws[h] = -s;
    }
    float wtc0, wts0, wtc1, wts1;
    {
        int m = (2044 * fg) % 2046;
        float s, c;
        __sincosf((float)m * (float)(PI_D / 1023.0), &s, &c);
        wtc0 = c; wts0 = -s;
        m = (2045 * fg) % 2046;
        __sincosf((float)m * (float)(PI_D / 1023.0), &s, &c);
        wtc1 = c; wts1 = -s;
    }

    const unsigned int* Cd = (const unsigned int*)Cl;   // dword idx = row*64 + lane
    const int tl0 = w * 7;                   // local frame base 0..49
    const int tg0 = tileMblk + tl0;
    float accm = 0.f;
    unsigned int ux[4], uy[4];
#pragma unroll
    for (int h = 0; h < 4; h++) {
        ux[h] = Cd[(2 * (tl0 + h)) * 64 + lane];
        uy[h] = Cd[(2 * (tl0 + h) + 1) * 64 + lane];
    }
#pragma unroll
    for (int d = 0; d < 7; d++) {
        const int tg = tg0 + d;
        if (tg < NFRAMES) {
            float xr = 0.f, xi = 0.f, yr = 0.f, yi = 0.f;
#pragma unroll
            for (int h = 0; h < 4; h++) {
                unsigned int vx = ux[(d + h) & 3];
                unsigned int vy = uy[(d + h) & 3];
                float vrx = __uint_as_float(vx << 16);
                float vix = __uint_as_float(vx & 0xFFFF0000u);
                float vry = __uint_as_float(vy << 16);
                float viy = __uint_as_float(vy & 0xFFFF0000u);
                xr += wc[h] * vrx - ws[h] * vix;
                xi += wc[h] * vix + ws[h] * vrx;
                yr += wc[h] * vry - ws[h] * viy;
                yi += wc[h] * viy + ws[h] * vry;
            }
            const float4 sd = S[tg + 4];
            xr += wtc0 * sd.x + wtc1 * sd.y;
            xi += wts0 * sd.x + wts1 * sd.y;
            yr += wtc0 * sd.z + wtc1 * sd.w;
            yi += wts0 * sd.z + wts1 * sd.w;
            float dm = sqrtf(xr * xr + xi * xi) - sqrtf(yr * yr + yi * yi);
            accm += dm * dm;
        }
        if (d < 6) {
            const int nb = tl0 + d + 4;      // refill slot d&3 with block tl0+d+4
            ux[d & 3] = Cd[(2 * nb) * 64 + lane];
            uy[d & 3] = Cd[(2 * nb + 1) * 64 + lane];
        }
    }
    atomicAdd(&msePart[lane], accm);
    __syncthreads();
    if (tid < 64) atomicAdd(&mse_sum[(tileN >> 1) + tid], msePart[tid]);
}

// ---------------- fused invw (FIRST) + gemm_combine dispatch ----------------------
// (512,6): 24 waves/CU = 3 blocks/CU (LDS 49.4KB x3 = 148KB < 160KB; VGPR meas. 44)
__global__ __launch_bounds__(512, 6) void gemm_combine_kernel(
    const char* __restrict__ A, const char* __restrict__ Bt,
    const float4* __restrict__ S, float* __restrict__ mse_sum,
    const float* __restrict__ ar, float* __restrict__ invW) {
    __shared__ __align__(16) char smem[16384 + 32768 + 256];
    const int bid = blockIdx.x;
    const int tid = threadIdx.x;
    if (bid < INVW_BLOCKS) {
        invw_body(bid, tid, smem, ar, invW);
    } else {
        const int b = bid - INVW_BLOCKS;
        gemm_combine_body(b & 15, b >> 4, tid, smem, A, Bt, S, mse_sum);
    }
}

// ---------------- final: out = sum_f mse_sum[f]*invW[f] / (4105*22528*1024) --------
__global__ void final_kernel(const float* __restrict__ mse_sum,
                             const float* __restrict__ invW,
                             float* __restrict__ out) {
    __shared__ float red[4];
    const int tid = threadIdx.x;
    float lo = 0.f;
    for (int f = tid; f < 1024; f += 256) lo += mse_sum[f] * invW[f];
    lo = wave_reduce(lo);
    if ((tid & 63) == 0) red[tid >> 6] = lo;
    __syncthreads();
    if (tid == 0) {
        float tot = red[0] + red[1] + red[2] + red[3];
        out[0] = tot * (float)(1.0 / (4105.0 * 22528.0 * 1024.0));
    }
}

extern "C" void kernel_launch(void* const* d_in, const int* in_sizes, int n_in,
                              void* d_out, int out_size, void* d_ws, size_t ws_size,
                              hipStream_t stream) {
    const float* x = (const float*)d_in[0];
    const float* y = (const float*)d_in[1];
    float* out = (float*)d_out;

    float* wsf = (float*)d_ws;
    float* mse_sum = wsf;                    // [0,1024) floats
    float* invW = wsf + 1024;                // [1024,2048)
    float* ar = wsf + 2080;                  // 2048*12 floats
    float4* S = (float4*)((char*)d_ws + 131072);     // 4352*16 = 69,632 B
    char* Ap = (char*)d_ws + 262144;                 // 520*8192 = 4,259,840 B fp8
    char* Bp = (char*)d_ws + 4521984;                // 128*8192 = 1,048,576 B fp8

    prep_kernel<<<PREP_BLOCKS, 256, 0, stream>>>(x, y, Ap, Bp, S, ar, wsf);
    gemm_combine_kernel<<<INVW_BLOCKS + GC_BLOCKS, 512, 0, stream>>>(Ap, Bp, S, mse_sum, ar, invW);
    final_kernel<<<1, 256, 0, stream>>>(mse_sum, invW, out);
}